// Round 1
// baseline (893.333 us; speedup 1.0000x reference)
//
#include <hip/hip_runtime.h>

// Problem constants (from reference)
#define Bc 2
#define Vc 5
#define Cc 32
#define Hc 256
#define Wc 320
#define Nc 40000

__device__ __forceinline__ float fetch_px(const float* __restrict__ fm, int x, int y) {
    if (x < 0 || x >= Wc || y < 0 || y >= Hc) return 0.0f;
    return fm[y * Wc + x];
}

// grid_sample bilinear, padding zeros, align_corners=False
__device__ __forceinline__ float bilin(const float* __restrict__ fm, float gx, float gy) {
    float ix = ((gx + 1.0f) * (float)Wc - 1.0f) * 0.5f;
    float iy = ((gy + 1.0f) * (float)Hc - 1.0f) * 0.5f;
    float x0f = floorf(ix), y0f = floorf(iy);
    float wx = ix - x0f, wy = iy - y0f;
    int x0 = (int)x0f, y0 = (int)y0f;
    float v00 = fetch_px(fm, x0,     y0);
    float v10 = fetch_px(fm, x0 + 1, y0);
    float v01 = fetch_px(fm, x0,     y0 + 1);
    float v11 = fetch_px(fm, x0 + 1, y0 + 1);
    return (v00 * (1.0f - wx) + v10 * wx) * (1.0f - wy)
         + (v01 * (1.0f - wx) + v11 * wx) * wy;
}

__global__ void __launch_bounds__(256)
fgf_kernel(const float* __restrict__ fm,
           const float* __restrict__ pts,
           const float* __restrict__ Kmat,
           const float* __restrict__ Emat,
           float* __restrict__ out_feat,
           float* __restrict__ out_grad)
{
    int idx = blockIdx.x * 256 + threadIdx.x;
    const int total = Bc * Vc * Cc * Nc;   // 12,800,000 < 2^31
    if (idx >= total) return;

    int n   = idx % Nc;
    int tcb = idx / Nc;
    int c   = tcb % Cc;
    int bv  = tcb / Cc;          // block-uniform (Nc*Cc multiple of 256)
    int b   = bv / Vc;

    // Load point (B,3,N layout)
    const float* p = pts + (b * 3) * Nc + n;
    float px = p[0];
    float py = p[Nc];
    float pz = p[2 * Nc];

    // Extrinsics (B,V,3,4), intrinsics (B,V,3,3) — wave-uniform loads
    const float* Ep = Emat + bv * 12;
    const float* Kp = Kmat + bv * 9;
    float x = Ep[0] * px + Ep[1] * py + Ep[2]  * pz + Ep[3];
    float y = Ep[4] * px + Ep[5] * py + Ep[6]  * pz + Ep[7];
    float z = Ep[8] * px + Ep[9] * py + Ep[10] * pz + Ep[11];

    float xz = x / z;
    float yz = y / z;
    float u = Kp[0] * xz + Kp[1] * yz + Kp[2];
    float v = Kp[3] * xz + Kp[4] * yz + Kp[5];

    float gx = (u - 0.5f) / (float)(Wc - 1) * 2.0f - 1.0f;
    float gy = (v - 0.5f) / (float)(Hc - 1) * 2.0f - 1.0f;
    const float dx = 2.0f / (float)(Wc - 1);
    const float dy = 2.0f / (float)(Hc - 1);

    const float* f = fm + (bv * Cc + c) * (Hc * Wc);

    float feat = bilin(f, gx,      gy);
    float fl   = bilin(f, gx - dx, gy);
    float fr   = bilin(f, gx + dx, gy);
    float ft   = bilin(f, gx,      gy - dy);
    float fb   = bilin(f, gx,      gy + dy);

    int o = (bv * Cc + c) * Nc + n;          // < 12.8M
    out_feat[o] = feat;
    float2 g = make_float2(0.5f * (fr - fl), 0.5f * (fb - ft));
    ((float2*)out_grad)[o] = g;              // coalesced 8B/lane
}

extern "C" void kernel_launch(void* const* d_in, const int* in_sizes, int n_in,
                              void* d_out, int out_size, void* d_ws, size_t ws_size,
                              hipStream_t stream) {
    const float* fm  = (const float*)d_in[0];  // feature_maps (B,V,C,H,W)
    const float* pts = (const float*)d_in[1];  // pts (B,3,N)
    const float* K   = (const float*)d_in[2];  // (B,V,3,3)
    const float* E   = (const float*)d_in[3];  // (B,V,3,4)

    float* out_feat = (float*)d_out;                                   // (B,V,C,N)
    float* out_grad = (float*)d_out + (size_t)Bc * Vc * Cc * Nc;       // (B,V,C,N,2)

    const int total = Bc * Vc * Cc * Nc;
    const int block = 256;
    const int grid  = (total + block - 1) / block;
    fgf_kernel<<<grid, block, 0, stream>>>(fm, pts, K, E, out_feat, out_grad);
}

// Round 2
// 341.084 us; speedup vs baseline: 2.6191x; 2.6191x over previous
//
#include <hip/hip_runtime.h>

// Problem constants (from reference)
#define Bc 2
#define Vc 5
#define Cc 32
#define Hc 256
#define Wc 320
#define Nc 40000
#define HWc (Hc * Wc)

// ---------------------------------------------------------------------------
// Pass 1: transpose (BV, C, H*W) -> (BV, H*W, C) so channels are contiguous.
// ---------------------------------------------------------------------------
__global__ void __launch_bounds__(256)
transpose_kernel(const float* __restrict__ fm, float* __restrict__ fmT)
{
    __shared__ float tile[Cc][65];   // +1 pad: conflict-free column reads
    const int bv  = blockIdx.y;
    const int hw0 = blockIdx.x * 64;
    const int t   = threadIdx.x;

    // Load: 32 rows (c) x 64 cols (hw), coalesced 256B per wave-instr
    const int tx = t & 63;
    const int ty = t >> 6;                  // 0..3
    const float* src = fm + (size_t)bv * Cc * HWc + hw0;
    #pragma unroll
    for (int i = 0; i < 8; ++i) {
        int c = ty * 8 + i;
        tile[c][tx] = src[(size_t)c * HWc + tx];
    }
    __syncthreads();

    // Store: for each hw, 32 contiguous channels; 256B contiguous per wave-instr
    const int cc = t & 31;
    const int hh = t >> 5;                  // 0..7
    float* dst = fmT + ((size_t)bv * HWc + hw0) * Cc + cc;
    #pragma unroll
    for (int i = 0; i < 8; ++i) {
        int hw = i * 8 + hh;
        dst[(size_t)hw * Cc] = tile[cc][hw];
    }
}

// ---------------------------------------------------------------------------
// Pass 2: project + 5 bilinear samples, channels vectorized via NHWC float4.
// One thread = (bv, n, cq); cq in [0,4) covers 8 channels (2 float4 slots).
// Channel of slot s=cq+4j, component k:  c = j*16 + cq*4 + k.
// ---------------------------------------------------------------------------
__device__ __forceinline__ void bilin_acc(const float4* __restrict__ base4, int cq,
                                          float ix, float iy, float coef,
                                          float a0[4], float a1[4])
{
    float x0f = floorf(ix), y0f = floorf(iy);
    float wx = ix - x0f, wy = iy - y0f;
    int x0 = (int)x0f, y0 = (int)y0f;
    float w00 = (1.0f - wx) * (1.0f - wy);
    float w10 = wx * (1.0f - wy);
    float w01 = (1.0f - wx) * wy;
    float w11 = wx * wy;
    float wgt[4] = {w00, w10, w01, w11};
    #pragma unroll
    for (int k = 0; k < 4; ++k) {
        int xc = x0 + (k & 1);
        int yc = y0 + (k >> 1);
        bool valid = (xc >= 0) & (xc < Wc) & (yc >= 0) & (yc < Hc);
        float wk = valid ? coef * wgt[k] : 0.0f;
        int xcl = min(max(xc, 0), Wc - 1);
        int ycl = min(max(yc, 0), Hc - 1);
        const float4* p = base4 + (((size_t)(ycl * Wc + xcl)) << 3) + cq;
        float4 v0 = p[0];   // channels cq*4   .. cq*4+3
        float4 v1 = p[4];   // channels 16+cq*4 .. 16+cq*4+3
        a0[0] = fmaf(wk, v0.x, a0[0]);
        a0[1] = fmaf(wk, v0.y, a0[1]);
        a0[2] = fmaf(wk, v0.z, a0[2]);
        a0[3] = fmaf(wk, v0.w, a0[3]);
        a1[0] = fmaf(wk, v1.x, a1[0]);
        a1[1] = fmaf(wk, v1.y, a1[1]);
        a1[2] = fmaf(wk, v1.z, a1[2]);
        a1[3] = fmaf(wk, v1.w, a1[3]);
    }
}

__global__ void __launch_bounds__(256)
fgf_main(const float* __restrict__ fmT,
         const float* __restrict__ pts,
         const float* __restrict__ Kmat,
         const float* __restrict__ Emat,
         float* __restrict__ out_feat,
         float* __restrict__ out_grad)
{
    int idx = blockIdx.x * 256 + threadIdx.x;    // < BV*N*4 = 1.6M
    int cq = idx & 3;
    int pn = idx >> 2;
    int n  = pn % Nc;
    int bv = pn / Nc;        // block-uniform (160000 threads per bv = 625 blocks)
    int b  = bv / Vc;

    // Point (B,3,N)
    const float* p = pts + (size_t)(b * 3) * Nc + n;
    float px = p[0];
    float py = p[Nc];
    float pz = p[2 * Nc];

    // Extrinsics (B,V,3,4), intrinsics (B,V,3,3) — wave-uniform
    const float* Ep = Emat + bv * 12;
    const float* Kp = Kmat + bv * 9;
    float x = Ep[0] * px + Ep[1] * py + Ep[2]  * pz + Ep[3];
    float y = Ep[4] * px + Ep[5] * py + Ep[6]  * pz + Ep[7];
    float z = Ep[8] * px + Ep[9] * py + Ep[10] * pz + Ep[11];
    float xz = x / z;
    float yz = y / z;
    float u = Kp[0] * xz + Kp[1] * yz + Kp[2];
    float v = Kp[3] * xz + Kp[4] * yz + Kp[5];

    // grid coords -> pixel coords (composed):
    // ix = (u-0.5)*W/(W-1) - 0.5 ; sample offset dx in pixels = W/(W-1)
    const float sxp = (float)Wc / (float)(Wc - 1);
    const float syp = (float)Hc / (float)(Hc - 1);
    float ix = (u - 0.5f) * sxp - 0.5f;
    float iy = (v - 0.5f) * syp - 0.5f;

    const float4* base4 = (const float4*)fmT + (size_t)bv * HWc * 8;

    float f0[4]  = {0, 0, 0, 0}, f1[4]  = {0, 0, 0, 0};
    float gx0[4] = {0, 0, 0, 0}, gx1[4] = {0, 0, 0, 0};
    float gy0[4] = {0, 0, 0, 0}, gy1[4] = {0, 0, 0, 0};

    bilin_acc(base4, cq, ix,       iy,       1.0f, f0,  f1);
    bilin_acc(base4, cq, ix - sxp, iy,      -0.5f, gx0, gx1);
    bilin_acc(base4, cq, ix + sxp, iy,       0.5f, gx0, gx1);
    bilin_acc(base4, cq, ix,       iy - syp, -0.5f, gy0, gy1);
    bilin_acc(base4, cq, ix,       iy + syp,  0.5f, gy0, gy1);

    // Outputs: feat (BV,C,N), grad (BV,C,N,2)
    size_t obase = (size_t)bv * Cc * Nc + n;
    float2* gp = (float2*)out_grad;
    #pragma unroll
    for (int k = 0; k < 4; ++k) {
        int c0 = cq * 4 + k;        // j=0
        int c1 = 16 + cq * 4 + k;   // j=1
        out_feat[obase + (size_t)c0 * Nc] = f0[k];
        out_feat[obase + (size_t)c1 * Nc] = f1[k];
        gp[obase + (size_t)c0 * Nc] = make_float2(gx0[k], gy0[k]);
        gp[obase + (size_t)c1 * Nc] = make_float2(gx1[k], gy1[k]);
    }
}

// ---------------------------------------------------------------------------
// Fallback (round-1 kernel) if ws is too small for the transposed copy.
// ---------------------------------------------------------------------------
__device__ __forceinline__ float fetch_px(const float* __restrict__ fm, int x, int y) {
    if (x < 0 || x >= Wc || y < 0 || y >= Hc) return 0.0f;
    return fm[y * Wc + x];
}
__device__ __forceinline__ float bilin(const float* __restrict__ fm, float ix, float iy) {
    float x0f = floorf(ix), y0f = floorf(iy);
    float wx = ix - x0f, wy = iy - y0f;
    int x0 = (int)x0f, y0 = (int)y0f;
    float v00 = fetch_px(fm, x0, y0);
    float v10 = fetch_px(fm, x0 + 1, y0);
    float v01 = fetch_px(fm, x0, y0 + 1);
    float v11 = fetch_px(fm, x0 + 1, y0 + 1);
    return (v00 * (1.0f - wx) + v10 * wx) * (1.0f - wy)
         + (v01 * (1.0f - wx) + v11 * wx) * wy;
}
__global__ void __launch_bounds__(256)
fgf_fallback(const float* __restrict__ fm,
             const float* __restrict__ pts,
             const float* __restrict__ Kmat,
             const float* __restrict__ Emat,
             float* __restrict__ out_feat,
             float* __restrict__ out_grad)
{
    int idx = blockIdx.x * 256 + threadIdx.x;
    const int total = Bc * Vc * Cc * Nc;
    if (idx >= total) return;
    int n = idx % Nc;
    int tcb = idx / Nc;
    int c = tcb % Cc;
    int bv = tcb / Cc;
    int b = bv / Vc;
    const float* p = pts + (size_t)(b * 3) * Nc + n;
    float px = p[0], py = p[Nc], pz = p[2 * Nc];
    const float* Ep = Emat + bv * 12;
    const float* Kp = Kmat + bv * 9;
    float x = Ep[0] * px + Ep[1] * py + Ep[2] * pz + Ep[3];
    float y = Ep[4] * px + Ep[5] * py + Ep[6] * pz + Ep[7];
    float z = Ep[8] * px + Ep[9] * py + Ep[10] * pz + Ep[11];
    float xz = x / z, yz = y / z;
    float u = Kp[0] * xz + Kp[1] * yz + Kp[2];
    float v = Kp[3] * xz + Kp[4] * yz + Kp[5];
    const float sxp = (float)Wc / (float)(Wc - 1);
    const float syp = (float)Hc / (float)(Hc - 1);
    float ix = (u - 0.5f) * sxp - 0.5f;
    float iy = (v - 0.5f) * syp - 0.5f;
    const float* f = fm + (size_t)(bv * Cc + c) * HWc;
    float feat = bilin(f, ix, iy);
    float fl = bilin(f, ix - sxp, iy);
    float fr = bilin(f, ix + sxp, iy);
    float ft = bilin(f, ix, iy - syp);
    float fb = bilin(f, ix, iy + syp);
    size_t o = (size_t)(bv * Cc + c) * Nc + n;
    out_feat[o] = feat;
    ((float2*)out_grad)[o] = make_float2(0.5f * (fr - fl), 0.5f * (fb - ft));
}

extern "C" void kernel_launch(void* const* d_in, const int* in_sizes, int n_in,
                              void* d_out, int out_size, void* d_ws, size_t ws_size,
                              hipStream_t stream) {
    const float* fm  = (const float*)d_in[0];  // (B,V,C,H,W)
    const float* pts = (const float*)d_in[1];  // (B,3,N)
    const float* K   = (const float*)d_in[2];  // (B,V,3,3)
    const float* E   = (const float*)d_in[3];  // (B,V,3,4)

    float* out_feat = (float*)d_out;                               // (B,V,C,N)
    float* out_grad = (float*)d_out + (size_t)Bc * Vc * Cc * Nc;   // (B,V,C,N,2)

    const size_t fmT_bytes = (size_t)Bc * Vc * Cc * HWc * sizeof(float); // 104,857,600

    if (ws_size >= fmT_bytes) {
        float* fmT = (float*)d_ws;
        dim3 tgrid(HWc / 64, Bc * Vc);
        transpose_kernel<<<tgrid, 256, 0, stream>>>(fm, fmT);
        const int total = Bc * Vc * Nc * 4;
        fgf_main<<<total / 256, 256, 0, stream>>>(fmT, pts, K, E, out_feat, out_grad);
    } else {
        const int total = Bc * Vc * Cc * Nc;
        fgf_fallback<<<(total + 255) / 256, 256, 0, stream>>>(fm, pts, K, E, out_feat, out_grad);
    }
}

// Round 3
// 278.282 us; speedup vs baseline: 3.2102x; 1.2257x over previous
//
#include <hip/hip_runtime.h>

// Problem constants (from reference)
#define Bc 2
#define Vc 5
#define Cc 32
#define Hc 256
#define Wc 320
#define Nc 40000
#define HWc (Hc * Wc)

typedef float v2f __attribute__((ext_vector_type(2)));

__device__ __forceinline__ unsigned bf16_rn(float x) {
    unsigned u = __float_as_uint(x);
    return (u + 0x7fffu + ((u >> 16) & 1u)) >> 16;   // round-to-nearest-even
}

// ---------------------------------------------------------------------------
// Pass 1: transpose + convert: fm (BV,C,HW) f32 -> fmT (BV,HW,C) bf16.
// Pixel row = 32 bf16 = 64B. Block: 64 hw x 32 c tile.
// ---------------------------------------------------------------------------
__global__ void __launch_bounds__(256)
transpose_bf16_kernel(const float* __restrict__ fm, unsigned short* __restrict__ fmT)
{
    __shared__ float tile[Cc][65];   // +1 pad: conflict-free both phases
    const int bv  = blockIdx.y;
    const int hw0 = blockIdx.x * 64;
    const int t   = threadIdx.x;

    const int tx = t & 63;
    const int ty = t >> 6;                  // 0..3
    const float* src = fm + (size_t)bv * Cc * HWc + hw0;
    #pragma unroll
    for (int i = 0; i < 8; ++i) {
        int c = ty * 8 + i;
        tile[c][tx] = __builtin_nontemporal_load(&src[(size_t)c * HWc + tx]);
    }
    __syncthreads();

    // Each thread packs one 16B chunk (8 channels) of one pixel.
    const int cq = t & 3;                   // chunk: channels cq*8 .. cq*8+7
    const int hw = t >> 2;                  // 0..63
    unsigned r[4];
    #pragma unroll
    for (int j = 0; j < 4; ++j) {
        float a = tile[cq * 8 + 2 * j][hw];
        float b = tile[cq * 8 + 2 * j + 1][hw];
        r[j] = bf16_rn(a) | (bf16_rn(b) << 16);
    }
    uint4* dst = (uint4*)(fmT + ((size_t)bv * HWc + hw0 + hw) * Cc) + cq;
    *dst = make_uint4(r[0], r[1], r[2], r[3]);
}

// ---------------------------------------------------------------------------
// Pass 2: project + 5 bilinear samples. Thread = (bv, n, cq); cq covers 8
// channels (one 16B bf16 chunk per corner). Depth-2 pipeline on samples.
// ---------------------------------------------------------------------------
__device__ __forceinline__ void corner_setup(float ix, float iy, float coef,
                                             float wk[4], int pix[4])
{
    float x0f = floorf(ix), y0f = floorf(iy);
    float wx = ix - x0f, wy = iy - y0f;
    int x0 = (int)x0f, y0 = (int)y0f;
    float wg0 = (1.0f - wx) * (1.0f - wy);
    float wg1 = wx * (1.0f - wy);
    float wg2 = (1.0f - wx) * wy;
    float wg3 = wx * wy;
    float wg[4] = {wg0, wg1, wg2, wg3};
    #pragma unroll
    for (int k = 0; k < 4; ++k) {
        int xc = x0 + (k & 1);
        int yc = y0 + (k >> 1);
        bool valid = (xc >= 0) & (xc < Wc) & (yc >= 0) & (yc < Hc);
        wk[k] = valid ? coef * wg[k] : 0.0f;
        int xcl = min(max(xc, 0), Wc - 1);
        int ycl = min(max(yc, 0), Hc - 1);
        pix[k] = ycl * Wc + xcl;
    }
}

__global__ void __launch_bounds__(256)
fgf_main(const unsigned short* __restrict__ fmT,
         const float* __restrict__ pts,
         const float* __restrict__ Kmat,
         const float* __restrict__ Emat,
         float* __restrict__ out_feat,
         float* __restrict__ out_grad)
{
    int idx = blockIdx.x * 256 + threadIdx.x;    // < BV*N*4 = 1.6M
    int cq = idx & 3;
    int pn = idx >> 2;
    int n  = pn % Nc;
    int bv = pn / Nc;        // block-uniform (160000 threads per bv)
    int b  = bv / Vc;

    // Point (B,3,N)
    const float* p = pts + (size_t)(b * 3) * Nc + n;
    float px = p[0];
    float py = p[Nc];
    float pz = p[2 * Nc];

    // Extrinsics (B,V,3,4), intrinsics (B,V,3,3) — wave-uniform
    const float* Ep = Emat + bv * 12;
    const float* Kp = Kmat + bv * 9;
    float x = Ep[0] * px + Ep[1] * py + Ep[2]  * pz + Ep[3];
    float y = Ep[4] * px + Ep[5] * py + Ep[6]  * pz + Ep[7];
    float z = Ep[8] * px + Ep[9] * py + Ep[10] * pz + Ep[11];
    float xz = x / z;
    float yz = y / z;
    float u = Kp[0] * xz + Kp[1] * yz + Kp[2];
    float v = Kp[3] * xz + Kp[4] * yz + Kp[5];

    const float sxp = (float)Wc / (float)(Wc - 1);   // pixel-space sample offset
    const float syp = (float)Hc / (float)(Hc - 1);
    float ix = (u - 0.5f) * sxp - 0.5f;
    float iy = (v - 0.5f) * syp - 0.5f;

    const uint4* base4 = (const uint4*)(fmT + (size_t)bv * HWc * Cc) + cq;

    const float ox[5] = {0.0f, -sxp, sxp, 0.0f, 0.0f};
    const float oy[5] = {0.0f, 0.0f, 0.0f, -syp, syp};
    const float cf[5] = {1.0f, -0.5f, 0.5f, -0.5f, 0.5f};
    const int   as[5] = {0, 1, 1, 2, 2};   // accumulator select: feat, gx, gy

    float acc[3][8];
    #pragma unroll
    for (int a = 0; a < 3; ++a)
        #pragma unroll
        for (int j = 0; j < 8; ++j) acc[a][j] = 0.0f;

    float wk[2][4];
    int   pix[2][4];
    uint4 rg[2][4];

    // prologue: sample 0
    corner_setup(ix + ox[0], iy + oy[0], cf[0], wk[0], pix[0]);
    #pragma unroll
    for (int k = 0; k < 4; ++k) rg[0][k] = base4[(size_t)pix[0][k] * 4];

    #pragma unroll
    for (int s = 0; s < 5; ++s) {
        int cur = s & 1;
        if (s < 4) {
            int nxt = cur ^ 1;
            corner_setup(ix + ox[s + 1], iy + oy[s + 1], cf[s + 1], wk[nxt], pix[nxt]);
            #pragma unroll
            for (int k = 0; k < 4; ++k) rg[nxt][k] = base4[(size_t)pix[nxt][k] * 4];
        }
        float* a = acc[as[s]];
        #pragma unroll
        for (int k = 0; k < 4; ++k) {
            uint4 w = rg[cur][k];
            float ww = wk[cur][k];
            a[0] = fmaf(ww, __uint_as_float(w.x << 16),          a[0]);
            a[1] = fmaf(ww, __uint_as_float(w.x & 0xffff0000u), a[1]);
            a[2] = fmaf(ww, __uint_as_float(w.y << 16),          a[2]);
            a[3] = fmaf(ww, __uint_as_float(w.y & 0xffff0000u), a[3]);
            a[4] = fmaf(ww, __uint_as_float(w.z << 16),          a[4]);
            a[5] = fmaf(ww, __uint_as_float(w.z & 0xffff0000u), a[5]);
            a[6] = fmaf(ww, __uint_as_float(w.w << 16),          a[6]);
            a[7] = fmaf(ww, __uint_as_float(w.w & 0xffff0000u), a[7]);
        }
    }

    // Outputs: feat (BV,C,N) f32, grad (BV,C,N,2) f32 — nontemporal (never re-read)
    size_t obase = (size_t)bv * Cc * Nc + n;
    v2f* gp = (v2f*)out_grad;
    #pragma unroll
    for (int j = 0; j < 8; ++j) {
        int c = cq * 8 + j;
        __builtin_nontemporal_store(acc[0][j], &out_feat[obase + (size_t)c * Nc]);
        v2f g = {acc[1][j], acc[2][j]};
        __builtin_nontemporal_store(g, &gp[obase + (size_t)c * Nc]);
    }
}

// ---------------------------------------------------------------------------
// Fallback (round-1 style, NCHW direct) if ws is too small.
// ---------------------------------------------------------------------------
__device__ __forceinline__ float fetch_px(const float* __restrict__ fm, int x, int y) {
    if (x < 0 || x >= Wc || y < 0 || y >= Hc) return 0.0f;
    return fm[y * Wc + x];
}
__device__ __forceinline__ float bilin(const float* __restrict__ fm, float ix, float iy) {
    float x0f = floorf(ix), y0f = floorf(iy);
    float wx = ix - x0f, wy = iy - y0f;
    int x0 = (int)x0f, y0 = (int)y0f;
    float v00 = fetch_px(fm, x0, y0);
    float v10 = fetch_px(fm, x0 + 1, y0);
    float v01 = fetch_px(fm, x0, y0 + 1);
    float v11 = fetch_px(fm, x0 + 1, y0 + 1);
    return (v00 * (1.0f - wx) + v10 * wx) * (1.0f - wy)
         + (v01 * (1.0f - wx) + v11 * wx) * wy;
}
__global__ void __launch_bounds__(256)
fgf_fallback(const float* __restrict__ fm,
             const float* __restrict__ pts,
             const float* __restrict__ Kmat,
             const float* __restrict__ Emat,
             float* __restrict__ out_feat,
             float* __restrict__ out_grad)
{
    int idx = blockIdx.x * 256 + threadIdx.x;
    const int total = Bc * Vc * Cc * Nc;
    if (idx >= total) return;
    int n = idx % Nc;
    int tcb = idx / Nc;
    int c = tcb % Cc;
    int bv = tcb / Cc;
    int b = bv / Vc;
    const float* p = pts + (size_t)(b * 3) * Nc + n;
    float px = p[0], py = p[Nc], pz = p[2 * Nc];
    const float* Ep = Emat + bv * 12;
    const float* Kp = Kmat + bv * 9;
    float x = Ep[0] * px + Ep[1] * py + Ep[2] * pz + Ep[3];
    float y = Ep[4] * px + Ep[5] * py + Ep[6] * pz + Ep[7];
    float z = Ep[8] * px + Ep[9] * py + Ep[10] * pz + Ep[11];
    float xz = x / z, yz = y / z;
    float u = Kp[0] * xz + Kp[1] * yz + Kp[2];
    float v = Kp[3] * xz + Kp[4] * yz + Kp[5];
    const float sxp = (float)Wc / (float)(Wc - 1);
    const float syp = (float)Hc / (float)(Hc - 1);
    float ix = (u - 0.5f) * sxp - 0.5f;
    float iy = (v - 0.5f) * syp - 0.5f;
    const float* f = fm + (size_t)(bv * Cc + c) * HWc;
    float feat = bilin(f, ix, iy);
    float fl = bilin(f, ix - sxp, iy);
    float fr = bilin(f, ix + sxp, iy);
    float ft = bilin(f, ix, iy - syp);
    float fb = bilin(f, ix, iy + syp);
    size_t o = (size_t)(bv * Cc + c) * HWc / HWc * 0 + (size_t)(bv * Cc + c) * Nc + n;
    out_feat[o] = feat;
    ((float2*)out_grad)[o] = make_float2(0.5f * (fr - fl), 0.5f * (fb - ft));
}

extern "C" void kernel_launch(void* const* d_in, const int* in_sizes, int n_in,
                              void* d_out, int out_size, void* d_ws, size_t ws_size,
                              hipStream_t stream) {
    const float* fm  = (const float*)d_in[0];  // (B,V,C,H,W)
    const float* pts = (const float*)d_in[1];  // (B,3,N)
    const float* K   = (const float*)d_in[2];  // (B,V,3,3)
    const float* E   = (const float*)d_in[3];  // (B,V,3,4)

    float* out_feat = (float*)d_out;                               // (B,V,C,N)
    float* out_grad = (float*)d_out + (size_t)Bc * Vc * Cc * Nc;   // (B,V,C,N,2)

    const size_t fmT_bytes = (size_t)Bc * Vc * Cc * HWc * sizeof(unsigned short); // 52,428,800

    if (ws_size >= fmT_bytes) {
        unsigned short* fmT = (unsigned short*)d_ws;
        dim3 tgrid(HWc / 64, Bc * Vc);
        transpose_bf16_kernel<<<tgrid, 256, 0, stream>>>(fm, fmT);
        const int total = Bc * Vc * Nc * 4;
        fgf_main<<<total / 256, 256, 0, stream>>>(fmT, pts, K, E, out_feat, out_grad);
    } else {
        const int total = Bc * Vc * Cc * Nc;
        fgf_fallback<<<(total + 255) / 256, 256, 0, stream>>>(fm, pts, K, E, out_feat, out_grad);
    }
}